// Round 10
// baseline (743.478 us; speedup 1.0000x reference)
//
#include <hip/hip_runtime.h>
#include <hip/hip_bf16.h>

typedef __attribute__((ext_vector_type(8))) short bf16x8;
typedef __attribute__((ext_vector_type(16))) float f32x16;
typedef __attribute__((ext_vector_type(4))) float f32x4;
typedef __attribute__((ext_vector_type(4))) unsigned int uint4v;
typedef unsigned short ushort_t;
typedef unsigned int uint_t;

#define N_NODES 16384
#define HD 128
#define NOUT 384
// packed B: pk[it][g][c][oct][l31][j]  it:0..129 (128,129 = U1,U2 tails)
//   byte offset = ((it*12+g)*16 + c*2 + oct)*512 + l31*16 + j*2 ; per-it = 98304 B

static __device__ __forceinline__ ushort_t f2bf(float f) {
  __hip_bfloat16 b = __float2bfloat16(f);
  return *reinterpret_cast<ushort_t*>(&b);
}

// ---------------- fused prep (384 threads/block) — unchanged ----------------
__global__ void prep_all(const float* __restrict__ A, const float* __restrict__ U1,
                         const float* __restrict__ U2, const float* __restrict__ nh,
                         ushort_t* __restrict__ pk, ushort_t* __restrict__ h1,
                         ushort_t* __restrict__ h2, float* __restrict__ h1tf) {
  __shared__ __align__(16) char smem[49152];
  const int b = blockIdx.x;
  const int t = threadIdx.x;

  if (b < 260) {
    short* spk = reinterpret_cast<short*>(smem);
    const int half = b & 1;
    const int gg = t >> 5, ll = t & 31;
    if (b < 256) {
      const int it = b >> 1;
      const size_t krow0 = (size_t)it * 128 + half * 64;
#pragma unroll 4
      for (int kl = 0; kl < 64; ++kl) {
        float v = A[(krow0 + kl) * NOUT + t];
        int cl = kl >> 4, oc = (kl >> 3) & 1, j = kl & 7;
        spk[(gg * 8 + cl * 2 + oc) * 256 + ll * 8 + j] = f2bf(v);
      }
    } else {
      const int u = (b - 256) >> 1;
      const float* U = u ? U2 : U1;
#pragma unroll 4
      for (int kl = 0; kl < 64; ++kl) {
        float v = U[(size_t)t * HD + half * 64 + kl];
        int cl = kl >> 4, oc = (kl >> 3) & 1, j = kl & 7;
        spk[(gg * 8 + cl * 2 + oc) * 256 + ll * 8 + j] = f2bf(v);
      }
    }
    __syncthreads();
    const int it_out = (b < 256) ? (b >> 1) : (128 + ((b - 256) >> 1));
    const int f = t * 64;
    const int g = f >> 11;
    const int inner = f & 2047;
    ushort_t* dst = pk + (size_t)it_out * 49152 + g * 4096 + half * 2048 + inner;
    const uint4* src = reinterpret_cast<const uint4*>(spk + f);
    uint4* d4 = reinterpret_cast<uint4*>(dst);
#pragma unroll
    for (int q = 0; q < 8; ++q) d4[q] = src[q];
  } else {
    if (t < 256) {
      float (*sm)[65] = reinterpret_cast<float(*)[65]>(smem);
      const int g = b - 260;            // 0..511
      const int mt = g & 255, jt = g >> 8;
      const int tx = t & 63, ty = t >> 6;
      const int m0 = mt * 64, j0 = jt * 64;
#pragma unroll
      for (int s = 0; s < 16; ++s) {
        int mm = ty + s * 4;
        float f1 = nh[(size_t)(m0 + mm) * 256 + j0 + tx];
        float f2 = nh[(size_t)(m0 + mm) * 256 + 128 + j0 + tx];
        h1[(size_t)(m0 + mm) * HD + j0 + tx] = f2bf(f1);
        h2[(size_t)(m0 + mm) * HD + j0 + tx] = f2bf(f2);
        sm[mm][tx] = f1;
      }
      __syncthreads();
#pragma unroll
      for (int s = 0; s < 16; ++s) {
        int jj = ty + s * 4;
        h1tf[(size_t)(j0 + jj) * N_NODES + m0 + tx] = sm[tx][jj];   // f32 transposed h1
      }
    }
  }
}

// ---------------- main GEMM: full-K blocks (no split-K, no reduce kernel) ----------
// R9's fixup poisoned every XCD's L2 with device-scope fences (2.3x regression).
// R10 keeps R9's GOAL (kill reduce2's 50MB round-trip + launch) with zero protocol:
// each block computes ALL 130 K-slices and writes `out` directly.
//   grid = 128 Mt x 6 Nt = 768 blocks, LDS 50688 -> 3 blocks/CU, EXACTLY one round.
//   3 desynced blocks/CU extends R8's proven lever (2 -> 3 independent barrier groups).
// Loop = R8's verified body (fused chain/read, counted vmcnt(5), raw barriers, ring-3,
// X/Y register pipeline, deferred TAILs). Even K-count (128) -> slice 128 (U1's
// B-fragments) lands in bbX at loop exit for free; U1 tail consumes it from registers.
// Wave tile 64m x 32n. Block = 4 waves (2wm x 2wn) = 128m x 64n.
#define PK_STEP 98304
#define SLICE_B 16896

#define STAGE(IT, R)                                                              \
  do {                                                                            \
    const char* s_ = pkbase + (size_t)(IT) * PK_STEP + stg;                       \
    char* d_ = ldsb + (R) * SLICE_B + wv * 4096;                                  \
    __builtin_amdgcn_global_load_lds((const uint_t*)(s_),        (uint_t*)(d_),        16, 0, 0); \
    __builtin_amdgcn_global_load_lds((const uint_t*)(s_ + 1024), (uint_t*)(d_ + 1024), 16, 0, 0); \
    __builtin_amdgcn_global_load_lds((const uint_t*)(s_ + 2048), (uint_t*)(d_ + 2048), 16, 0, 0); \
    __builtin_amdgcn_global_load_lds((const uint_t*)(s_ + 3072), (uint_t*)(d_ + 3072), 16, 0, 0); \
    const int ith_ = (IT) < 128 ? (IT) : 127;                                     \
    const char* h_ = reinterpret_cast<const char*>(                               \
                         h1tf + (size_t)ith_ * N_NODES + Mt * 128) + wv * 128;    \
    if (lane < 8)                                                                 \
      __builtin_amdgcn_global_load_lds((const uint_t*)(h_ + lane * 16),           \
          (uint_t*)(ldsb + (R) * SLICE_B + 16384 + wv * 128), 16, 0, 0);          \
  } while (0)

#define READN(BBN, SN0, SN1, RN)                                                  \
  do {                                                                            \
    const char* lb_ = ldsb + (RN) * SLICE_B;                                      \
    const char* bb_ = lb_ + wn * 8192 + oct * 512 + l31 * 16;                     \
    SN0 = *reinterpret_cast<const float*>(lb_ + 16384 + (wm * 64 + l31) * 4);     \
    SN1 = *reinterpret_cast<const float*>(lb_ + 16384 + (wm * 64 + 32 + l31) * 4);\
    _Pragma("unroll")                                                             \
    for (int c = 0; c < 8; ++c)                                                   \
      BBN[c] = *reinterpret_cast<const uint4v*>(bb_ + c * 1024);                  \
  } while (0)

// chain on BBC (current slice) fused with LDS reads of BBN (next slice)
#define CHAINRD(BBC, PC0, PC1, BBN, SN0, SN1, RN)                                 \
  do {                                                                            \
    const char* lb_ = ldsb + (RN) * SLICE_B;                                      \
    const char* bb_ = lb_ + wn * 8192 + oct * 512 + l31 * 16;                     \
    SN0 = *reinterpret_cast<const float*>(lb_ + 16384 + (wm * 64 + l31) * 4);     \
    SN1 = *reinterpret_cast<const float*>(lb_ + 16384 + (wm * 64 + 32 + l31) * 4);\
    PC0 = vz; PC1 = vz;                                                           \
    _Pragma("unroll")                                                             \
    for (int c = 0; c < 8; ++c) {                                                 \
      BBN[c] = *reinterpret_cast<const uint4v*>(bb_ + c * 1024);                  \
      bf16x8 f_ = __builtin_bit_cast(bf16x8, BBC[c]);                             \
      PC0 = __builtin_amdgcn_mfma_f32_32x32x16_bf16(                              \
          f_, __builtin_bit_cast(bf16x8, h2u[0][c]), PC0, 0, 0, 0);               \
      PC1 = __builtin_amdgcn_mfma_f32_32x32x16_bf16(                              \
          f_, __builtin_bit_cast(bf16x8, h2u[1][c]), PC1, 0, 0, 0);               \
    }                                                                             \
  } while (0)

#define TAIL(S0_, S1_, PP0, PP1)                                                  \
  do {                                                                            \
    _Pragma("unroll")                                                             \
    for (int rr = 0; rr < 16; ++rr) {                                             \
      acc[0][rr] += (S0_) * PP0[rr];                                              \
      acc[1][rr] += (S1_) * PP1[rr];                                              \
    }                                                                             \
  } while (0)

__global__ __launch_bounds__(256, 3)
void gemm_kernel(const ushort_t* __restrict__ pk, const ushort_t* __restrict__ h1bf,
                 const ushort_t* __restrict__ h2bf, const float* __restrict__ h1tf,
                 const float* __restrict__ u2b, float* __restrict__ out) {
  __shared__ __align__(16) char ldsb[3 * SLICE_B];   // 50688 B -> 3 blocks/CU

  const int tid = threadIdx.x;
  const int bid = blockIdx.x;
  // XCD-clustering swizzle (bijective: 768 = 8*96): each XCD works one Nt slab.
  const int v  = (bid & 7) * 96 + (bid >> 3);
  const int Mt = v & 127;
  const int Nt = v >> 7;        // 0..5

  const int lane = tid & 63, wv = tid >> 6;     // wv 0..3
  const int l31 = lane & 31, oct = lane >> 5;
  const int wm = wv >> 1, wn = wv & 1;          // 2m x 2n wave grid
  const int mbase = Mt * 128 + wm * 64;
  const int n0w = Nt * 64 + wn * 32;
  const int g0 = Nt * 2;                        // first 32-col group staged by this block

  // resident h2 fragments (used as MFMA B-operand): rows mbase+ms*32+l31
  uint4v h2u[2][8];
#pragma unroll
  for (int ms = 0; ms < 2; ++ms) {
    const ushort_t* hp = h2bf + (size_t)(mbase + ms * 32 + l31) * HD + oct * 8;
#pragma unroll
    for (int c = 0; c < 8; ++c)
      h2u[ms][c] = *reinterpret_cast<const uint4v*>(hp + c * 16);
  }

  // acc init with bias (transposed layout):
  // acc[ms][4q+j] = out[mbase+ms*32+l31][n0w + 8q + 4*oct + j]
  f32x16 acc[2];
#pragma unroll
  for (int qq = 0; qq < 4; ++qq) {
    f32x4 bq = *reinterpret_cast<const f32x4*>(u2b + n0w + 8 * qq + 4 * oct);
#pragma unroll
    for (int j = 0; j < 4; ++j) { acc[0][qq * 4 + j] = bq[j]; acc[1][qq * 4 + j] = bq[j]; }
  }

  // per-block slice base: 16 KB contiguous starting at g0*8192
  const char* pkbase = reinterpret_cast<const char*>(pk) + (size_t)g0 * 8192;
  const int stg = wv * 4096 + lane * 16;        // per-wave pk staging chunk (4 KB)

  const f32x16 vz = (f32x16)(0.0f);

  // prologue: stage slice 0 -> slot0, slice 1 -> slot1 (10 loads in flight/wave)
  STAGE(0, 0);
  STAGE(1, 1);
  asm volatile("s_waitcnt vmcnt(5)" ::: "memory");   // stage(0) landed (this wave)
  __builtin_amdgcn_s_barrier();                      // ... for all waves
  uint4v bbX[8], bbY[8];
  f32x16 pX0, pX1, pY0 = vz, pY1 = vz;
  float sX0, sX1, sY0 = 0.0f, sY1 = 0.0f;            // zero => first (dummy) tail adds 0
  READN(bbX, sX0, sX1, 0);                           // slice 0 fragments -> regs

  int rn = 1, rsb = 2;                               // ring idx: next-read slot, stage slot
  for (int it = 0; it + 1 < 128; it += 2) {
    // ---- even body: chain it (X) fused with read it+1 (Y); tail it-1 (old Y) ----
    {
      const float t0 = sY0, t1 = sY1;
      STAGE(it + 2, rsb); rsb = (rsb == 2) ? 0 : rsb + 1;
      asm volatile("s_waitcnt vmcnt(5)" ::: "memory");  // stage(it+1) landed (this wave)
      __builtin_amdgcn_s_barrier();                     // ... all waves -> slot[it+1] valid
      CHAINRD(bbX, pX0, pX1, bbY, sY0, sY1, rn); rn = (rn == 2) ? 0 : rn + 1;
      TAIL(t0, t1, pY0, pY1);
    }
    // ---- odd body: chain it+1 (Y) fused with read it+2 (X); tail it (X) ----
    {
      const float t0 = sX0, t1 = sX1;
      STAGE(it + 3, rsb); rsb = (rsb == 2) ? 0 : rsb + 1;
      asm volatile("s_waitcnt vmcnt(5)" ::: "memory");
      __builtin_amdgcn_s_barrier();
      CHAINRD(bbY, pY0, pY1, bbX, sX0, sX1, rn); rn = (rn == 2) ? 0 : rn + 1;
      TAIL(t0, t1, pX0, pX1);
    }
  }
  // After the loop: slices 0..127 chained; TAIL of 127 pending (pY); bbX holds
  // slice 128 = U1's B-fragments (read in the last odd body); slice 129 staged.
  TAIL(sY0, sY1, pY0, pY1);              // finish slice 127

  // U1 tail (slice 128, fragments already in bbX): acc += mfma(bb, h1 fragment)
#pragma unroll
  for (int c = 0; c < 8; ++c) {
    bf16x8 bfr = __builtin_bit_cast(bf16x8, bbX[c]);
#pragma unroll
    for (int ms = 0; ms < 2; ++ms) {
      bf16x8 a = *reinterpret_cast<const bf16x8*>(
          h1bf + (size_t)(mbase + ms * 32 + l31) * HD + c * 16 + oct * 8);
      acc[ms] = __builtin_amdgcn_mfma_f32_32x32x16_bf16(bfr, a, acc[ms], 0, 0, 0);
    }
  }

  // U2 tail (slice 129, staged into slot rn=129%3=0): wait for ALL waves' stage.
  asm volatile("s_waitcnt vmcnt(0)" ::: "memory");
  __builtin_amdgcn_s_barrier();
  {
    float du0, du1;
    READN(bbY, du0, du1, rn);            // slice 129 fragments (scales are dup junk)
#pragma unroll
    for (int c = 0; c < 8; ++c) {
      bf16x8 bfr = __builtin_bit_cast(bf16x8, bbY[c]);
#pragma unroll
      for (int ms = 0; ms < 2; ++ms) {
        acc[ms] = __builtin_amdgcn_mfma_f32_32x32x16_bf16(
            bfr, __builtin_bit_cast(bf16x8, h2u[ms][c]), acc[ms], 0, 0, 0);
      }
    }
  }

  // epilogue: write out directly (transposed regs -> aligned f32x4 row-chunks).
  // acc[ms][4q+j] -> out[mbase+ms*32+l31][n0w + 8q + 4*oct + j]
#pragma unroll
  for (int ms = 0; ms < 2; ++ms) {
    float* rowp = out + (size_t)(mbase + ms * 32 + l31) * NOUT + n0w + 4 * oct;
#pragma unroll
    for (int qq = 0; qq < 4; ++qq) {
      f32x4 o;
      o[0] = acc[ms][qq * 4 + 0];
      o[1] = acc[ms][qq * 4 + 1];
      o[2] = acc[ms][qq * 4 + 2];
      o[3] = acc[ms][qq * 4 + 3];
      *reinterpret_cast<f32x4*>(rowp + 8 * qq) = o;
    }
  }
}

extern "C" void kernel_launch(void* const* d_in, const int* in_sizes, int n_in,
                              void* d_out, int out_size, void* d_ws, size_t ws_size,
                              hipStream_t stream) {
  const float* nh  = (const float*)d_in[0];   // (16384, 2, 128)
  const float* A   = (const float*)d_in[1];   // (128, 128, 384)
  const float* U1  = (const float*)d_in[2];   // (384, 128)
  const float* U2  = (const float*)d_in[3];   // (384, 128)
  const float* U2b = (const float*)d_in[4];   // (384,)

  char* ws = (char*)d_ws;
  ushort_t* pk   = (ushort_t*)(ws);                 // 130*98304    = 12,779,520 B
  ushort_t* h1bf = (ushort_t*)(ws + 12779520);      // 16384*128*2 =  4,194,304
  ushort_t* h2bf = (ushort_t*)(ws + 16973824);      //               4,194,304
  float*    h1tf = (float*)(ws + 21168128);         // 128*16384*4 =  8,388,608  (total ~29.6 MB)

  prep_all<<<dim3(772), 384, 0, stream>>>(A, U1, U2, nh, pk, h1bf, h2bf, h1tf);
  gemm_kernel<<<dim3(768), 256, 0, stream>>>(pk, h1bf, h2bf, h1tf, U2b, (float*)d_out);
}

// Round 11
// 300.323 us; speedup vs baseline: 2.4756x; 2.4756x over previous
//
#include <hip/hip_runtime.h>
#include <hip/hip_bf16.h>

typedef __attribute__((ext_vector_type(8))) short bf16x8;
typedef __attribute__((ext_vector_type(16))) float f32x16;
typedef __attribute__((ext_vector_type(4))) float f32x4;
typedef __attribute__((ext_vector_type(4))) unsigned int uint4v;
typedef unsigned short ushort_t;
typedef unsigned int uint_t;

#define N_NODES 16384
#define HD 128
#define NOUT 384
#define PART_ELEMS 6291456    // 16384*384
// packed B: pk[it][g][c][oct][l31][j]  it:0..129 (128,129 = U1,U2 tails)
//   byte offset = ((it*12+g)*16 + c*2 + oct)*512 + l31*16 + j*2 ; per-it = 98304 B

static __device__ __forceinline__ ushort_t f2bf(float f) {
  __hip_bfloat16 b = __float2bfloat16(f);
  return *reinterpret_cast<ushort_t*>(&b);
}

// ---------------- fused prep (384 threads/block) — unchanged ----------------
__global__ void prep_all(const float* __restrict__ A, const float* __restrict__ U1,
                         const float* __restrict__ U2, const float* __restrict__ nh,
                         ushort_t* __restrict__ pk, ushort_t* __restrict__ h1,
                         ushort_t* __restrict__ h2, float* __restrict__ h1tf) {
  __shared__ __align__(16) char smem[49152];
  const int b = blockIdx.x;
  const int t = threadIdx.x;

  if (b < 260) {
    short* spk = reinterpret_cast<short*>(smem);
    const int half = b & 1;
    const int gg = t >> 5, ll = t & 31;
    if (b < 256) {
      const int it = b >> 1;
      const size_t krow0 = (size_t)it * 128 + half * 64;
#pragma unroll 4
      for (int kl = 0; kl < 64; ++kl) {
        float v = A[(krow0 + kl) * NOUT + t];
        int cl = kl >> 4, oc = (kl >> 3) & 1, j = kl & 7;
        spk[(gg * 8 + cl * 2 + oc) * 256 + ll * 8 + j] = f2bf(v);
      }
    } else {
      const int u = (b - 256) >> 1;
      const float* U = u ? U2 : U1;
#pragma unroll 4
      for (int kl = 0; kl < 64; ++kl) {
        float v = U[(size_t)t * HD + half * 64 + kl];
        int cl = kl >> 4, oc = (kl >> 3) & 1, j = kl & 7;
        spk[(gg * 8 + cl * 2 + oc) * 256 + ll * 8 + j] = f2bf(v);
      }
    }
    __syncthreads();
    const int it_out = (b < 256) ? (b >> 1) : (128 + ((b - 256) >> 1));
    const int f = t * 64;
    const int g = f >> 11;
    const int inner = f & 2047;
    ushort_t* dst = pk + (size_t)it_out * 49152 + g * 4096 + half * 2048 + inner;
    const uint4* src = reinterpret_cast<const uint4*>(spk + f);
    uint4* d4 = reinterpret_cast<uint4*>(dst);
#pragma unroll
    for (int q = 0; q < 8; ++q) d4[q] = src[q];
  } else {
    if (t < 256) {
      float (*sm)[65] = reinterpret_cast<float(*)[65]>(smem);
      const int g = b - 260;            // 0..511
      const int mt = g & 255, jt = g >> 8;
      const int tx = t & 63, ty = t >> 6;
      const int m0 = mt * 64, j0 = jt * 64;
#pragma unroll
      for (int s = 0; s < 16; ++s) {
        int mm = ty + s * 4;
        float f1 = nh[(size_t)(m0 + mm) * 256 + j0 + tx];
        float f2 = nh[(size_t)(m0 + mm) * 256 + 128 + j0 + tx];
        h1[(size_t)(m0 + mm) * HD + j0 + tx] = f2bf(f1);
        h2[(size_t)(m0 + mm) * HD + j0 + tx] = f2bf(f2);
        sm[mm][tx] = f1;
      }
      __syncthreads();
#pragma unroll
      for (int s = 0; s < 16; ++s) {
        int jj = ty + s * 4;
        h1tf[(size_t)(j0 + jj) * N_NODES + m0 + tx] = sm[tx][jj];   // f32 transposed h1
      }
    }
  }
}

// ---------------- main GEMM: R8 structure (verified 292 µs) + setprio (T5) --------
// R9 post-mortem: device-scope fence/spin fixup poisoned L2 chip-wide (2.3x). R10
// post-mortem: launch_bounds(256,3) capped VGPR at ~170 < the ~230 live regs ->
// scratch spill, FETCH 74MB->2GB (3.6x). Both reverted. This is EXACTLY R8 (split-K,
// 2 blocks/CU, fused chain/read, counted vmcnt(5), ring-3, X/Y reg pipeline,
// deferred TAILs, part[2]+reduce2) with ONE isolated delta:
//   setprio(1) around the MFMA cluster (T5). R8 has the role-diversity T5 needs
//   (2 desynced blocks/CU; m218b +21-39% with role-split, m190 null in lockstep).
// Wave tile 64m x 32n. Block = 4 waves (2wm x 2wn) = 128m x 64n.
// grid = 128 Mt x 6 Nt x 2 ks = 1536 blocks @ 2/CU resident -> exactly 3 rounds.
#define PK_STEP 98304
#define SLICE_B 16896

#define STAGE(IT, R)                                                              \
  do {                                                                            \
    const char* s_ = pkbase + (size_t)(IT) * PK_STEP + stg;                       \
    char* d_ = ldsb + (R) * SLICE_B + wv * 4096;                                  \
    __builtin_amdgcn_global_load_lds((const uint_t*)(s_),        (uint_t*)(d_),        16, 0, 0); \
    __builtin_amdgcn_global_load_lds((const uint_t*)(s_ + 1024), (uint_t*)(d_ + 1024), 16, 0, 0); \
    __builtin_amdgcn_global_load_lds((const uint_t*)(s_ + 2048), (uint_t*)(d_ + 2048), 16, 0, 0); \
    __builtin_amdgcn_global_load_lds((const uint_t*)(s_ + 3072), (uint_t*)(d_ + 3072), 16, 0, 0); \
    const int ith_ = (IT) < 128 ? (IT) : 127;                                     \
    const char* h_ = reinterpret_cast<const char*>(                               \
                         h1tf + (size_t)ith_ * N_NODES + Mt * 128) + wv * 128;    \
    if (lane < 8)                                                                 \
      __builtin_amdgcn_global_load_lds((const uint_t*)(h_ + lane * 16),           \
          (uint_t*)(ldsb + (R) * SLICE_B + 16384 + wv * 128), 16, 0, 0);          \
  } while (0)

#define READN(BBN, SN0, SN1, RN)                                                  \
  do {                                                                            \
    const char* lb_ = ldsb + (RN) * SLICE_B;                                      \
    const char* bb_ = lb_ + wn * 8192 + oct * 512 + l31 * 16;                     \
    SN0 = *reinterpret_cast<const float*>(lb_ + 16384 + (wm * 64 + l31) * 4);     \
    SN1 = *reinterpret_cast<const float*>(lb_ + 16384 + (wm * 64 + 32 + l31) * 4);\
    _Pragma("unroll")                                                             \
    for (int c = 0; c < 8; ++c)                                                   \
      BBN[c] = *reinterpret_cast<const uint4v*>(bb_ + c * 1024);                  \
  } while (0)

// chain on BBC (current slice) fused with LDS reads of BBN (next slice); T5 bracket
#define CHAINRD(BBC, PC0, PC1, BBN, SN0, SN1, RN)                                 \
  do {                                                                            \
    const char* lb_ = ldsb + (RN) * SLICE_B;                                      \
    const char* bb_ = lb_ + wn * 8192 + oct * 512 + l31 * 16;                     \
    SN0 = *reinterpret_cast<const float*>(lb_ + 16384 + (wm * 64 + l31) * 4);     \
    SN1 = *reinterpret_cast<const float*>(lb_ + 16384 + (wm * 64 + 32 + l31) * 4);\
    PC0 = vz; PC1 = vz;                                                           \
    __builtin_amdgcn_s_setprio(1);                                                \
    _Pragma("unroll")                                                             \
    for (int c = 0; c < 8; ++c) {                                                 \
      BBN[c] = *reinterpret_cast<const uint4v*>(bb_ + c * 1024);                  \
      bf16x8 f_ = __builtin_bit_cast(bf16x8, BBC[c]);                             \
      PC0 = __builtin_amdgcn_mfma_f32_32x32x16_bf16(                              \
          f_, __builtin_bit_cast(bf16x8, h2u[0][c]), PC0, 0, 0, 0);               \
      PC1 = __builtin_amdgcn_mfma_f32_32x32x16_bf16(                              \
          f_, __builtin_bit_cast(bf16x8, h2u[1][c]), PC1, 0, 0, 0);               \
    }                                                                             \
    __builtin_amdgcn_s_setprio(0);                                                \
  } while (0)

#define CHAIN(BBC, PC0, PC1)                                                      \
  do {                                                                            \
    PC0 = vz; PC1 = vz;                                                           \
    __builtin_amdgcn_s_setprio(1);                                                \
    _Pragma("unroll")                                                             \
    for (int c = 0; c < 8; ++c) {                                                 \
      bf16x8 f_ = __builtin_bit_cast(bf16x8, BBC[c]);                             \
      PC0 = __builtin_amdgcn_mfma_f32_32x32x16_bf16(                              \
          f_, __builtin_bit_cast(bf16x8, h2u[0][c]), PC0, 0, 0, 0);               \
      PC1 = __builtin_amdgcn_mfma_f32_32x32x16_bf16(                              \
          f_, __builtin_bit_cast(bf16x8, h2u[1][c]), PC1, 0, 0, 0);               \
    }                                                                             \
    __builtin_amdgcn_s_setprio(0);                                                \
  } while (0)

#define TAIL(S0_, S1_, PP0, PP1)                                                  \
  do {                                                                            \
    _Pragma("unroll")                                                             \
    for (int rr = 0; rr < 16; ++rr) {                                             \
      acc[0][rr] += (S0_) * PP0[rr];                                              \
      acc[1][rr] += (S1_) * PP1[rr];                                              \
    }                                                                             \
  } while (0)

__global__ __launch_bounds__(256, 2)
void gemm_kernel(const ushort_t* __restrict__ pk, const ushort_t* __restrict__ h1bf,
                 const ushort_t* __restrict__ h2bf, const float* __restrict__ h1tf,
                 const float* __restrict__ u2b, float* __restrict__ part) {
  __shared__ __align__(16) char ldsb[3 * SLICE_B];   // 50688 B

  const int tid = threadIdx.x;
  const int bid = blockIdx.x;
  // XCD-clustering swizzle (bijective: 1536 = 8*192).
  const int v  = (bid & 7) * 192 + (bid >> 3);
  const int Mt = v & 127;
  const int q  = v >> 7;        // 0..11
  const int Nt = q >> 1;
  const int ks = q & 1;

  const int lane = tid & 63, wv = tid >> 6;     // wv 0..3
  const int l31 = lane & 31, oct = lane >> 5;
  const int wm = wv >> 1, wn = wv & 1;          // 2m x 2n wave grid
  const int mbase = Mt * 128 + wm * 64;
  const int n0w = Nt * 64 + wn * 32;
  const int g0 = Nt * 2;                        // first 32-col group staged by this block

  // resident h2 fragments (used as MFMA B-operand): rows mbase+ms*32+l31
  uint4v h2u[2][8];
#pragma unroll
  for (int ms = 0; ms < 2; ++ms) {
    const ushort_t* hp = h2bf + (size_t)(mbase + ms * 32 + l31) * HD + oct * 8;
#pragma unroll
    for (int c = 0; c < 8; ++c)
      h2u[ms][c] = *reinterpret_cast<const uint4v*>(hp + c * 16);
  }

  // acc init (transposed layout): acc[ms][r] = out[mbase+ms*32+l31][n0w+(r&3)+8*(r>>2)+4*oct]
  f32x16 acc[2];
  if (ks) {
#pragma unroll
    for (int qq = 0; qq < 4; ++qq) {
      f32x4 bq = *reinterpret_cast<const f32x4*>(u2b + n0w + 8 * qq + 4 * oct);
#pragma unroll
      for (int j = 0; j < 4; ++j) { acc[0][qq * 4 + j] = bq[j]; acc[1][qq * 4 + j] = bq[j]; }
    }
  } else {
    acc[0] = (f32x16)(0.0f);
    acc[1] = (f32x16)(0.0f);
  }

  const int it0 = ks ? 65 : 0;
  const int it1 = ks ? 128 : 65;   // nit = 65 / 63, both odd

  // per-block slice base: 16 KB contiguous starting at g0*8192
  const char* pkbase = reinterpret_cast<const char*>(pk) + (size_t)g0 * 8192;
  const int stg = wv * 4096 + lane * 16;        // per-wave pk staging chunk (4 KB)

  const f32x16 vz = (f32x16)(0.0f);

  // prologue: stage it0 -> slot0, it0+1 -> slot1 (10 loads in flight/wave)
  STAGE(it0, 0);
  STAGE(it0 + 1, 1);
  asm volatile("s_waitcnt vmcnt(5)" ::: "memory");   // stage(it0) landed (this wave)
  __builtin_amdgcn_s_barrier();                      // ... for all waves
  uint4v bbX[8], bbY[8];
  f32x16 pX0, pX1, pY0 = vz, pY1 = vz;
  float sX0, sX1, sY0 = 0.0f, sY1 = 0.0f;            // zero => first (dummy) tail adds 0
  READN(bbX, sX0, sX1, 0);                           // slice it0 fragments -> regs

  int rn = 1, rsb = 2;                               // ring idx: next-read slot, stage slot
  for (int it = it0; it + 1 < it1; it += 2) {
    // ---- even body: chain it (X) fused with read it+1 (Y); tail it-1 (old Y) ----
    {
      const float t0 = sY0, t1 = sY1;
      STAGE(it + 2, rsb); rsb = (rsb == 2) ? 0 : rsb + 1;
      asm volatile("s_waitcnt vmcnt(5)" ::: "memory");  // stage(it+1) landed (this wave)
      __builtin_amdgcn_s_barrier();                     // ... all waves -> slot[it+1] valid
      CHAINRD(bbX, pX0, pX1, bbY, sY0, sY1, rn); rn = (rn == 2) ? 0 : rn + 1;
      TAIL(t0, t1, pY0, pY1);
    }
    // ---- odd body: chain it+1 (Y) fused with read it+2 (X); tail it (X) ----
    {
      const float t0 = sX0, t1 = sX1;
      STAGE(it + 3, rsb); rsb = (rsb == 2) ? 0 : rsb + 1;
      asm volatile("s_waitcnt vmcnt(5)" ::: "memory");
      __builtin_amdgcn_s_barrier();
      CHAINRD(bbY, pY0, pY1, bbX, sX0, sX1, rn); rn = (rn == 2) ? 0 : rn + 1;
      TAIL(t0, t1, pX0, pX1);
    }
  }
  // final slice it1-1 (nit odd): fragments in bbX, scales in sX
  {
    TAIL(sY0, sY1, pY0, pY1);            // finish slice it1-2
    CHAIN(bbX, pX0, pX1);                // slice it1-1
    TAIL(sX0, sX1, pX0, pX1);            // final tail
  }

  if (ks) {
    // U1 tail (it=128): accT += mfma(A=bb, B=h1 fragment)  — one-time global loads
    const char* bt = reinterpret_cast<const char*>(pk) +
                     (size_t)128 * PK_STEP + (size_t)((g0 + wn) * 16 + oct) * 512 +
                     (size_t)l31 * 16;
#pragma unroll
    for (int c = 0; c < 8; ++c) {
      bf16x8 bfr = __builtin_bit_cast(bf16x8, *reinterpret_cast<const uint4v*>(bt + c * 1024));
#pragma unroll
      for (int ms = 0; ms < 2; ++ms) {
        bf16x8 a = *reinterpret_cast<const bf16x8*>(
            h1bf + (size_t)(mbase + ms * 32 + l31) * HD + c * 16 + oct * 8);
        acc[ms] = __builtin_amdgcn_mfma_f32_32x32x16_bf16(bfr, a, acc[ms], 0, 0, 0);
      }
    }
    // U2 tail (it=129): accT += mfma(A=bb, B=h2u resident)
    const char* bt2 = bt + PK_STEP;
#pragma unroll
    for (int c = 0; c < 8; ++c) {
      bf16x8 bfr = __builtin_bit_cast(bf16x8, *reinterpret_cast<const uint4v*>(bt2 + c * 1024));
#pragma unroll
      for (int ms = 0; ms < 2; ++ms) {
        acc[ms] = __builtin_amdgcn_mfma_f32_32x32x16_bf16(
            bfr, __builtin_bit_cast(bf16x8, h2u[ms][c]), acc[ms], 0, 0, 0);
      }
    }
  }

  // epilogue: transposed regs regroup into aligned f32x4 row-chunks of out.
  // acc[ms][4q+j] -> out[mbase+ms*32+l31][n0w + 8q + 4*oct + j]
  float* my = part + (size_t)ks * PART_ELEMS;
#pragma unroll
  for (int ms = 0; ms < 2; ++ms) {
    float* rowp = my + (size_t)(mbase + ms * 32 + l31) * NOUT + n0w + 4 * oct;
#pragma unroll
    for (int qq = 0; qq < 4; ++qq) {
      f32x4 o;
      o[0] = acc[ms][qq * 4 + 0];
      o[1] = acc[ms][qq * 4 + 1];
      o[2] = acc[ms][qq * 4 + 2];
      o[3] = acc[ms][qq * 4 + 3];
      *reinterpret_cast<f32x4*>(rowp + 8 * qq) = o;
    }
  }
}

// ---------------- reduce: out = P0 + P1 (bias already in P1) ----------------
__global__ void reduce2(const float* __restrict__ part, float* __restrict__ out) {
  int i = blockIdx.x * 256 + threadIdx.x;          // 1,572,864 float4s
  float4 a = reinterpret_cast<const float4*>(part)[i];
  float4 b = reinterpret_cast<const float4*>(part + PART_ELEMS)[i];
  float4 o;
  o.x = a.x + b.x; o.y = a.y + b.y; o.z = a.z + b.z; o.w = a.w + b.w;
  reinterpret_cast<float4*>(out)[i] = o;
}

extern "C" void kernel_launch(void* const* d_in, const int* in_sizes, int n_in,
                              void* d_out, int out_size, void* d_ws, size_t ws_size,
                              hipStream_t stream) {
  const float* nh  = (const float*)d_in[0];   // (16384, 2, 128)
  const float* A   = (const float*)d_in[1];   // (128, 128, 384)
  const float* U1  = (const float*)d_in[2];   // (384, 128)
  const float* U2  = (const float*)d_in[3];   // (384, 128)
  const float* U2b = (const float*)d_in[4];   // (384,)

  char* ws = (char*)d_ws;
  ushort_t* pk   = (ushort_t*)(ws);                 // 130*98304    = 12,779,520 B
  ushort_t* h1bf = (ushort_t*)(ws + 12779520);      // 16384*128*2 =  4,194,304
  ushort_t* h2bf = (ushort_t*)(ws + 16973824);      //               4,194,304
  float*    h1tf = (float*)(ws + 21168128);         // 128*16384*4 =  8,388,608
  float*    part = (float*)(ws + 29556736);         // 2*25,165,824 = 50,331,648  (total ~79.9 MB)

  prep_all<<<dim3(772), 384, 0, stream>>>(A, U1, U2, nh, pk, h1bf, h2bf, h1tf);
  gemm_kernel<<<dim3(1536), 256, 0, stream>>>(pk, h1bf, h2bf, h1tf, U2b, part);
  reduce2<<<dim3(6144), 256, 0, stream>>>(part, (float*)d_out);
}

// Round 12
// 292.085 us; speedup vs baseline: 2.5454x; 1.0282x over previous
//
#include <hip/hip_runtime.h>
#include <hip/hip_bf16.h>

typedef __attribute__((ext_vector_type(8))) short bf16x8;
typedef __attribute__((ext_vector_type(16))) float f32x16;
typedef __attribute__((ext_vector_type(4))) float f32x4;
typedef __attribute__((ext_vector_type(4))) unsigned int uint4v;
typedef unsigned short ushort_t;
typedef unsigned int uint_t;

#define N_NODES 16384
#define HD 128
#define NOUT 384
#define PART_ELEMS 6291456    // 16384*384
// packed B: pk[it][g][c][oct][l31][j]  it:0..129 (128,129 = U1,U2 tails)
//   byte offset = ((it*12+g)*16 + c*2 + oct)*512 + l31*16 + j*2 ; per-it = 98304 B

static __device__ __forceinline__ ushort_t f2bf(float f) {
  __hip_bfloat16 b = __float2bfloat16(f);
  return *reinterpret_cast<ushort_t*>(&b);
}

// ---------------- fused prep (384 threads/block) ----------------
// R12: A-pack/U-pack LDS writes vectorized — each thread's 8 consecutive j-slots
// are contiguous shorts -> build bf16x8 in regs, ONE ds_write_b128 per group of 8
// (was 64 scalar ds_write_b16 with 256-short strides = heavy bank conflicts).
__global__ void prep_all(const float* __restrict__ A, const float* __restrict__ U1,
                         const float* __restrict__ U2, const float* __restrict__ nh,
                         ushort_t* __restrict__ pk, ushort_t* __restrict__ h1,
                         ushort_t* __restrict__ h2, float* __restrict__ h1tf) {
  __shared__ __align__(16) char smem[49152];
  const int b = blockIdx.x;
  const int t = threadIdx.x;

  if (b < 260) {
    short* spk = reinterpret_cast<short*>(smem);
    const int half = b & 1;
    const int gg = t >> 5, ll = t & 31;
    if (b < 256) {
      const int it = b >> 1;
      const size_t krow0 = (size_t)it * 128 + half * 64;
#pragma unroll
      for (int grp = 0; grp < 8; ++grp) {          // grp = cl*2+oc ; j = 0..7
        ushort_t tmp[8];
#pragma unroll
        for (int j = 0; j < 8; ++j)
          tmp[j] = f2bf(A[(krow0 + grp * 8 + j) * NOUT + t]);
        *reinterpret_cast<uint4v*>(&spk[(gg * 8 + grp) * 256 + ll * 8]) =
            *reinterpret_cast<const uint4v*>(tmp);
      }
    } else {
      const int u = (b - 256) >> 1;
      const float* U = u ? U2 : U1;
#pragma unroll
      for (int grp = 0; grp < 8; ++grp) {
        const float4* up = reinterpret_cast<const float4*>(
            U + (size_t)t * HD + half * 64 + grp * 8);
        float4 va = up[0], vb = up[1];
        ushort_t tmp[8];
        tmp[0] = f2bf(va.x); tmp[1] = f2bf(va.y); tmp[2] = f2bf(va.z); tmp[3] = f2bf(va.w);
        tmp[4] = f2bf(vb.x); tmp[5] = f2bf(vb.y); tmp[6] = f2bf(vb.z); tmp[7] = f2bf(vb.w);
        *reinterpret_cast<uint4v*>(&spk[(gg * 8 + grp) * 256 + ll * 8]) =
            *reinterpret_cast<const uint4v*>(tmp);
      }
    }
    __syncthreads();
    const int it_out = (b < 256) ? (b >> 1) : (128 + ((b - 256) >> 1));
    const int f = t * 64;
    const int g = f >> 11;
    const int inner = f & 2047;
    ushort_t* dst = pk + (size_t)it_out * 49152 + g * 4096 + half * 2048 + inner;
    const uint4* src = reinterpret_cast<const uint4*>(spk + f);
    uint4* d4 = reinterpret_cast<uint4*>(dst);
#pragma unroll
    for (int q = 0; q < 8; ++q) d4[q] = src[q];
  } else {
    if (t < 256) {
      float (*sm)[65] = reinterpret_cast<float(*)[65]>(smem);
      const int g = b - 260;            // 0..511
      const int mt = g & 255, jt = g >> 8;
      const int tx = t & 63, ty = t >> 6;
      const int m0 = mt * 64, j0 = jt * 64;
#pragma unroll
      for (int s = 0; s < 16; ++s) {
        int mm = ty + s * 4;
        float f1 = nh[(size_t)(m0 + mm) * 256 + j0 + tx];
        float f2 = nh[(size_t)(m0 + mm) * 256 + 128 + j0 + tx];
        h1[(size_t)(m0 + mm) * HD + j0 + tx] = f2bf(f1);
        h2[(size_t)(m0 + mm) * HD + j0 + tx] = f2bf(f2);
        sm[mm][tx] = f1;
      }
      __syncthreads();
#pragma unroll
      for (int s = 0; s < 16; ++s) {
        int jj = ty + s * 4;
        h1tf[(size_t)(j0 + jj) * N_NODES + m0 + tx] = sm[tx][jj];   // f32 transposed h1
      }
    }
  }
}

// ---------------- main GEMM: R8 structure (verified 292 µs) + start stagger --------
// R11 isolated setprio: HURT (193->202, MfmaUtil 53->49) — twin blocks are phase-
// ALIGNED clones, no role diversity. R12's single delta: one-time ~1150cy s_sleep
// for one of each co-resident pair (bid bit 8 under round-robin dispatch) forces
// anti-phase: one block's CHAIN overlaps the other's READ/STAGE/TAIL permanently
// (blocks are self-paced; the offset persists). If the dispatch model is wrong the
// stagger is a harmless shuffle; cost 0.5 µs.
// Wave tile 64m x 32n. Block = 4 waves (2wm x 2wn) = 128m x 64n.
// grid = 128 Mt x 6 Nt x 2 ks = 1536 blocks @ 2/CU resident -> exactly 3 rounds.
#define PK_STEP 98304
#define SLICE_B 16896

#define STAGE(IT, R)                                                              \
  do {                                                                            \
    const char* s_ = pkbase + (size_t)(IT) * PK_STEP + stg;                       \
    char* d_ = ldsb + (R) * SLICE_B + wv * 4096;                                  \
    __builtin_amdgcn_global_load_lds((const uint_t*)(s_),        (uint_t*)(d_),        16, 0, 0); \
    __builtin_amdgcn_global_load_lds((const uint_t*)(s_ + 1024), (uint_t*)(d_ + 1024), 16, 0, 0); \
    __builtin_amdgcn_global_load_lds((const uint_t*)(s_ + 2048), (uint_t*)(d_ + 2048), 16, 0, 0); \
    __builtin_amdgcn_global_load_lds((const uint_t*)(s_ + 3072), (uint_t*)(d_ + 3072), 16, 0, 0); \
    const int ith_ = (IT) < 128 ? (IT) : 127;                                     \
    const char* h_ = reinterpret_cast<const char*>(                               \
                         h1tf + (size_t)ith_ * N_NODES + Mt * 128) + wv * 128;    \
    if (lane < 8)                                                                 \
      __builtin_amdgcn_global_load_lds((const uint_t*)(h_ + lane * 16),           \
          (uint_t*)(ldsb + (R) * SLICE_B + 16384 + wv * 128), 16, 0, 0);          \
  } while (0)

#define READN(BBN, SN0, SN1, RN)                                                  \
  do {                                                                            \
    const char* lb_ = ldsb + (RN) * SLICE_B;                                      \
    const char* bb_ = lb_ + wn * 8192 + oct * 512 + l31 * 16;                     \
    SN0 = *reinterpret_cast<const float*>(lb_ + 16384 + (wm * 64 + l31) * 4);     \
    SN1 = *reinterpret_cast<const float*>(lb_ + 16384 + (wm * 64 + 32 + l31) * 4);\
    _Pragma("unroll")                                                             \
    for (int c = 0; c < 8; ++c)                                                   \
      BBN[c] = *reinterpret_cast<const uint4v*>(bb_ + c * 1024);                  \
  } while (0)

// chain on BBC (current slice) fused with LDS reads of BBN (next slice)
#define CHAINRD(BBC, PC0, PC1, BBN, SN0, SN1, RN)                                 \
  do {                                                                            \
    const char* lb_ = ldsb + (RN) * SLICE_B;                                      \
    const char* bb_ = lb_ + wn * 8192 + oct * 512 + l31 * 16;                     \
    SN0 = *reinterpret_cast<const float*>(lb_ + 16384 + (wm * 64 + l31) * 4);     \
    SN1 = *reinterpret_cast<const float*>(lb_ + 16384 + (wm * 64 + 32 + l31) * 4);\
    PC0 = vz; PC1 = vz;                                                           \
    _Pragma("unroll")                                                             \
    for (int c = 0; c < 8; ++c) {                                                 \
      BBN[c] = *reinterpret_cast<const uint4v*>(bb_ + c * 1024);                  \
      bf16x8 f_ = __builtin_bit_cast(bf16x8, BBC[c]);                             \
      PC0 = __builtin_amdgcn_mfma_f32_32x32x16_bf16(                              \
          f_, __builtin_bit_cast(bf16x8, h2u[0][c]), PC0, 0, 0, 0);               \
      PC1 = __builtin_amdgcn_mfma_f32_32x32x16_bf16(                              \
          f_, __builtin_bit_cast(bf16x8, h2u[1][c]), PC1, 0, 0, 0);               \
    }                                                                             \
  } while (0)

#define CHAIN(BBC, PC0, PC1)                                                      \
  do {                                                                            \
    PC0 = vz; PC1 = vz;                                                           \
    _Pragma("unroll")                                                             \
    for (int c = 0; c < 8; ++c) {                                                 \
      bf16x8 f_ = __builtin_bit_cast(bf16x8, BBC[c]);                             \
      PC0 = __builtin_amdgcn_mfma_f32_32x32x16_bf16(                              \
          f_, __builtin_bit_cast(bf16x8, h2u[0][c]), PC0, 0, 0, 0);               \
      PC1 = __builtin_amdgcn_mfma_f32_32x32x16_bf16(                              \
          f_, __builtin_bit_cast(bf16x8, h2u[1][c]), PC1, 0, 0, 0);               \
    }                                                                             \
  } while (0)

#define TAIL(S0_, S1_, PP0, PP1)                                                  \
  do {                                                                            \
    _Pragma("unroll")                                                             \
    for (int rr = 0; rr < 16; ++rr) {                                             \
      acc[0][rr] += (S0_) * PP0[rr];                                              \
      acc[1][rr] += (S1_) * PP1[rr];                                              \
    }                                                                             \
  } while (0)

__global__ __launch_bounds__(256, 2)
void gemm_kernel(const ushort_t* __restrict__ pk, const ushort_t* __restrict__ h1bf,
                 const ushort_t* __restrict__ h2bf, const float* __restrict__ h1tf,
                 const float* __restrict__ u2b, float* __restrict__ part) {
  __shared__ __align__(16) char ldsb[3 * SLICE_B];   // 50688 B

  const int tid = threadIdx.x;
  const int bid = blockIdx.x;
  // XCD-clustering swizzle (bijective: 1536 = 8*192).
  const int v  = (bid & 7) * 192 + (bid >> 3);
  const int Mt = v & 127;
  const int q  = v >> 7;        // 0..11
  const int Nt = q >> 1;
  const int ks = q & 1;

  // Anti-phase stagger: under round-robin dispatch, co-resident CU twins differ in
  // bid bit 8 (k=bid>>3 per XCD; same CU = k, k+32). Shift one twin by ~half a slice.
  if ((bid >> 8) & 1) __builtin_amdgcn_s_sleep(18);   // ~1150 cy, once

  const int lane = tid & 63, wv = tid >> 6;     // wv 0..3
  const int l31 = lane & 31, oct = lane >> 5;
  const int wm = wv >> 1, wn = wv & 1;          // 2m x 2n wave grid
  const int mbase = Mt * 128 + wm * 64;
  const int n0w = Nt * 64 + wn * 32;
  const int g0 = Nt * 2;                        // first 32-col group staged by this block

  // resident h2 fragments (used as MFMA B-operand): rows mbase+ms*32+l31
  uint4v h2u[2][8];
#pragma unroll
  for (int ms = 0; ms < 2; ++ms) {
    const ushort_t* hp = h2bf + (size_t)(mbase + ms * 32 + l31) * HD + oct * 8;
#pragma unroll
    for (int c = 0; c < 8; ++c)
      h2u[ms][c] = *reinterpret_cast<const uint4v*>(hp + c * 16);
  }

  // acc init (transposed layout): acc[ms][r] = out[mbase+ms*32+l31][n0w+(r&3)+8*(r>>2)+4*oct]
  f32x16 acc[2];
  if (ks) {
#pragma unroll
    for (int qq = 0; qq < 4; ++qq) {
      f32x4 bq = *reinterpret_cast<const f32x4*>(u2b + n0w + 8 * qq + 4 * oct);
#pragma unroll
      for (int j = 0; j < 4; ++j) { acc[0][qq * 4 + j] = bq[j]; acc[1][qq * 4 + j] = bq[j]; }
    }
  } else {
    acc[0] = (f32x16)(0.0f);
    acc[1] = (f32x16)(0.0f);
  }

  const int it0 = ks ? 65 : 0;
  const int it1 = ks ? 128 : 65;   // nit = 65 / 63, both odd

  // per-block slice base: 16 KB contiguous starting at g0*8192
  const char* pkbase = reinterpret_cast<const char*>(pk) + (size_t)g0 * 8192;
  const int stg = wv * 4096 + lane * 16;        // per-wave pk staging chunk (4 KB)

  const f32x16 vz = (f32x16)(0.0f);

  // prologue: stage it0 -> slot0, it0+1 -> slot1 (10 loads in flight/wave)
  STAGE(it0, 0);
  STAGE(it0 + 1, 1);
  asm volatile("s_waitcnt vmcnt(5)" ::: "memory");   // stage(it0) landed (this wave)
  __builtin_amdgcn_s_barrier();                      // ... for all waves
  uint4v bbX[8], bbY[8];
  f32x16 pX0, pX1, pY0 = vz, pY1 = vz;
  float sX0, sX1, sY0 = 0.0f, sY1 = 0.0f;            // zero => first (dummy) tail adds 0
  READN(bbX, sX0, sX1, 0);                           // slice it0 fragments -> regs

  int rn = 1, rsb = 2;                               // ring idx: next-read slot, stage slot
  for (int it = it0; it + 1 < it1; it += 2) {
    // ---- even body: chain it (X) fused with read it+1 (Y); tail it-1 (old Y) ----
    {
      const float t0 = sY0, t1 = sY1;
      STAGE(it + 2, rsb); rsb = (rsb == 2) ? 0 : rsb + 1;
      asm volatile("s_waitcnt vmcnt(5)" ::: "memory");  // stage(it+1) landed (this wave)
      __builtin_amdgcn_s_barrier();                     // ... all waves -> slot[it+1] valid
      CHAINRD(bbX, pX0, pX1, bbY, sY0, sY1, rn); rn = (rn == 2) ? 0 : rn + 1;
      TAIL(t0, t1, pY0, pY1);
    }
    // ---- odd body: chain it+1 (Y) fused with read it+2 (X); tail it (X) ----
    {
      const float t0 = sX0, t1 = sX1;
      STAGE(it + 3, rsb); rsb = (rsb == 2) ? 0 : rsb + 1;
      asm volatile("s_waitcnt vmcnt(5)" ::: "memory");
      __builtin_amdgcn_s_barrier();
      CHAINRD(bbY, pY0, pY1, bbX, sX0, sX1, rn); rn = (rn == 2) ? 0 : rn + 1;
      TAIL(t0, t1, pX0, pX1);
    }
  }
  // final slice it1-1 (nit odd): fragments in bbX, scales in sX
  {
    TAIL(sY0, sY1, pY0, pY1);            // finish slice it1-2
    CHAIN(bbX, pX0, pX1);                // slice it1-1
    TAIL(sX0, sX1, pX0, pX1);            // final tail
  }

  if (ks) {
    // U1 tail (it=128): accT += mfma(A=bb, B=h1 fragment)  — one-time global loads
    const char* bt = reinterpret_cast<const char*>(pk) +
                     (size_t)128 * PK_STEP + (size_t)((g0 + wn) * 16 + oct) * 512 +
                     (size_t)l31 * 16;
#pragma unroll
    for (int c = 0; c < 8; ++c) {
      bf16x8 bfr = __builtin_bit_cast(bf16x8, *reinterpret_cast<const uint4v*>(bt + c * 1024));
#pragma unroll
      for (int ms = 0; ms < 2; ++ms) {
        bf16x8 a = *reinterpret_cast<const bf16x8*>(
            h1bf + (size_t)(mbase + ms * 32 + l31) * HD + c * 16 + oct * 8);
        acc[ms] = __builtin_amdgcn_mfma_f32_32x32x16_bf16(bfr, a, acc[ms], 0, 0, 0);
      }
    }
    // U2 tail (it=129): accT += mfma(A=bb, B=h2u resident)
    const char* bt2 = bt + PK_STEP;
#pragma unroll
    for (int c = 0; c < 8; ++c) {
      bf16x8 bfr = __builtin_bit_cast(bf16x8, *reinterpret_cast<const uint4v*>(bt2 + c * 1024));
#pragma unroll
      for (int ms = 0; ms < 2; ++ms) {
        acc[ms] = __builtin_amdgcn_mfma_f32_32x32x16_bf16(
            bfr, __builtin_bit_cast(bf16x8, h2u[ms][c]), acc[ms], 0, 0, 0);
      }
    }
  }

  // epilogue: transposed regs regroup into aligned f32x4 row-chunks of out.
  // acc[ms][4q+j] -> out[mbase+ms*32+l31][n0w + 8q + 4*oct + j]
  float* my = part + (size_t)ks * PART_ELEMS;
#pragma unroll
  for (int ms = 0; ms < 2; ++ms) {
    float* rowp = my + (size_t)(mbase + ms * 32 + l31) * NOUT + n0w + 4 * oct;
#pragma unroll
    for (int qq = 0; qq < 4; ++qq) {
      f32x4 o;
      o[0] = acc[ms][qq * 4 + 0];
      o[1] = acc[ms][qq * 4 + 1];
      o[2] = acc[ms][qq * 4 + 2];
      o[3] = acc[ms][qq * 4 + 3];
      *reinterpret_cast<f32x4*>(rowp + 8 * qq) = o;
    }
  }
}

// ---------------- reduce: out = P0 + P1 (bias already in P1) ----------------
__global__ void reduce2(const float* __restrict__ part, float* __restrict__ out) {
  int i = blockIdx.x * 256 + threadIdx.x;          // 1,572,864 float4s
  float4 a = reinterpret_cast<const float4*>(part)[i];
  float4 b = reinterpret_cast<const float4*>(part + PART_ELEMS)[i];
  float4 o;
  o.x = a.x + b.x; o.y = a.y + b.y; o.z = a.z + b.z; o.w = a.w + b.w;
  reinterpret_cast<float4*>(out)[i] = o;
}

extern "C" void kernel_launch(void* const* d_in, const int* in_sizes, int n_in,
                              void* d_out, int out_size, void* d_ws, size_t ws_size,
                              hipStream_t stream) {
  const float* nh  = (const float*)d_in[0];   // (16384, 2, 128)
  const float* A   = (const float*)d_in[1];   // (128, 128, 384)
  const float* U1  = (const float*)d_in[2];   // (384, 128)
  const float* U2  = (const float*)d_in[3];   // (384, 128)
  const float* U2b = (const float*)d_in[4];   // (384,)

  char* ws = (char*)d_ws;
  ushort_t* pk   = (ushort_t*)(ws);                 // 130*98304    = 12,779,520 B
  ushort_t* h1bf = (ushort_t*)(ws + 12779520);      // 16384*128*2 =  4,194,304
  ushort_t* h2bf = (ushort_t*)(ws + 16973824);      //               4,194,304
  float*    h1tf = (float*)(ws + 21168128);         // 128*16384*4 =  8,388,608
  float*    part = (float*)(ws + 29556736);         // 2*25,165,824 = 50,331,648  (total ~79.9 MB)

  prep_all<<<dim3(772), 384, 0, stream>>>(A, U1, U2, nh, pk, h1bf, h2bf, h1tf);
  gemm_kernel<<<dim3(1536), 256, 0, stream>>>(pk, h1bf, h2bf, h1tf, U2b, part);
  reduce2<<<dim3(6144), 256, 0, stream>>>(part, (float*)d_out);
}